// Round 9
// baseline (274.571 us; speedup 1.0000x reference)
//
#include <hip/hip_runtime.h>
#include <hip/hip_bf16.h>

#define NN 20000
#define MM 32
#define EE 20
#define HH 128

typedef __attribute__((ext_vector_type(8))) short bf16x8;
typedef __attribute__((ext_vector_type(4))) float f32x4;

// ---------- helpers ----------
__device__ __forceinline__ float bf_lo(unsigned int u) {
    return __uint_as_float(u << 16);
}
__device__ __forceinline__ float bf_hi(unsigned int u) {
    return __uint_as_float(u & 0xFFFF0000u);
}
__device__ __forceinline__ unsigned int pack_bf2(float lo, float hi) {
    unsigned int a = __float_as_uint(lo);
    unsigned int b = __float_as_uint(hi);
    a += 0x7FFFu + ((a >> 16) & 1u);
    b += 0x7FFFu + ((b >> 16) & 1u);
    return (a >> 16) | (b & 0xFFFF0000u);
}
__device__ __forceinline__ unsigned short bf16r(float v) {
    unsigned int u = __float_as_uint(v);
    u += 0x7FFFu + ((u >> 16) & 1u);
    return (unsigned short)(u >> 16);
}
__device__ __forceinline__ float softplusf(float x) {
    return fmaxf(x, 0.f) + __logf(1.f + __expf(-fabsf(x)));
}

// ---------- kernel 1: build Wcat (128 x 1024, pair-encoded cols) ----------
__global__ void build_wcat(const float* __restrict__ cheW,
                           const float* __restrict__ vdwW,
                           float* __restrict__ Wcat) {
    int t = blockIdx.x * 256 + threadIdx.x;   // < 131072
    int k = t >> 10;
    int c = t & 1023;
    int b = c >> 9, sec = (c >> 8) & 1, h = (c >> 1) & 127, slot = c & 1;
    const float* W = b ? vdwW : cheW;
    int row = (sec ? 256 : 0) + k;
    Wcat[t] = W[row * 256 + slot * 128 + h];
}

// ---------- kernel 2: build Bfrag (MFMA B fragments of WfW, bf16) + biasP ----------
// Bfrag element index: (((b*2+wold)*8+tc)*64 + l)*8 + i   (2048 fragments)
__global__ void build_bfrag(const float* __restrict__ cheWf, const float* __restrict__ cheBf,
                            const float* __restrict__ cheW,  const float* __restrict__ cheBfull,
                            const float* __restrict__ vdwWf, const float* __restrict__ vdwBf,
                            const float* __restrict__ vdwW,  const float* __restrict__ vdwBfull,
                            unsigned short* __restrict__ Bfrag, float* __restrict__ biasP) {
    int t = blockIdx.x * 256 + threadIdx.x;   // < 2048
    int b = t >> 10, w = (t >> 9) & 1, tc = (t >> 6) & 7, l = t & 63;
    int lhi = l >> 4, llo = l & 15;
    int h = w * 64 + (tc >> 1) * 16 + llo;    // < 128
    int slot = tc & 1;
    int jcol = slot * 128 + h;                // < 256
    const float* Wf = b ? vdwWf : cheWf;
    const float* W  = b ? vdwW  : cheW;

    unsigned short o[8];
#pragma unroll
    for (int i = 0; i < 8; ++i) {
        int k = lhi * 8 + i;
        float a = 0.f;
        if (k < EE)
            for (int h2 = 0; h2 < 128; ++h2)
                a = fmaf(Wf[k * 128 + h2], W[(128 + h2) * 256 + jcol], a);
        o[i] = bf16r(a);
    }
#pragma unroll
    for (int i = 0; i < 8; ++i) Bfrag[t * 8 + i] = o[i];

    if (t < 512) {
        int bb = t >> 8, sl = (t >> 7) & 1, hh = t & 127;
        int jc = sl * 128 + hh;
        const float* bfv   = bb ? vdwBf    : cheBf;
        const float* Wb    = bb ? vdwW     : cheW;
        const float* bfull = bb ? vdwBfull : cheBfull;
        float s = bfull[jc];
        for (int h2 = 0; h2 < 128; ++h2)
            s = fmaf(bfv[h2], Wb[(128 + h2) * 256 + jc], s);
        biasP[t] = s;
    }
}

// ---------- kernel 3: proj GEMM  P[n][512] (bf16x2 packed) = nodes @ Wcat ----------
__global__ __launch_bounds__(256) void proj_kernel(const float* __restrict__ nodes,
                                                   const float* __restrict__ Wcat,
                                                   unsigned int* __restrict__ P) {
    __shared__ float ln[16 * 128];
    int n0 = blockIdx.x * 16;
    int t = threadIdx.x;
    for (int i = t; i < 2048; i += 256) ln[i] = nodes[n0 * 128 + i];
    __syncthreads();

    float4 acc[16];
#pragma unroll
    for (int i = 0; i < 16; ++i) acc[i] = make_float4(0.f, 0.f, 0.f, 0.f);

    int c0 = t * 4;
    for (int k = 0; k < 128; k += 4) {
        float4 w0 = *(const float4*)&Wcat[(k + 0) * 1024 + c0];
        float4 w1 = *(const float4*)&Wcat[(k + 1) * 1024 + c0];
        float4 w2 = *(const float4*)&Wcat[(k + 2) * 1024 + c0];
        float4 w3 = *(const float4*)&Wcat[(k + 3) * 1024 + c0];
#pragma unroll
        for (int ni = 0; ni < 16; ++ni) {
            float4 nv = *(const float4*)&ln[ni * 128 + k];
            acc[ni].x = fmaf(nv.x, w0.x, acc[ni].x);
            acc[ni].y = fmaf(nv.x, w0.y, acc[ni].y);
            acc[ni].z = fmaf(nv.x, w0.z, acc[ni].z);
            acc[ni].w = fmaf(nv.x, w0.w, acc[ni].w);
            acc[ni].x = fmaf(nv.y, w1.x, acc[ni].x);
            acc[ni].y = fmaf(nv.y, w1.y, acc[ni].y);
            acc[ni].z = fmaf(nv.y, w1.z, acc[ni].z);
            acc[ni].w = fmaf(nv.y, w1.w, acc[ni].w);
            acc[ni].x = fmaf(nv.z, w2.x, acc[ni].x);
            acc[ni].y = fmaf(nv.z, w2.y, acc[ni].y);
            acc[ni].z = fmaf(nv.z, w2.z, acc[ni].z);
            acc[ni].w = fmaf(nv.z, w2.w, acc[ni].w);
            acc[ni].x = fmaf(nv.w, w3.x, acc[ni].x);
            acc[ni].y = fmaf(nv.w, w3.y, acc[ni].y);
            acc[ni].z = fmaf(nv.w, w3.z, acc[ni].z);
            acc[ni].w = fmaf(nv.w, w3.w, acc[ni].w);
        }
    }
#pragma unroll
    for (int ni = 0; ni < 16; ++ni) {
        uint2 uu;
        uu.x = pack_bf2(acc[ni].x, acc[ni].y);
        uu.y = pack_bf2(acc[ni].z, acc[ni].w);
        *(uint2*)&P[(n0 + ni) * 512 + t * 2] = uu;
    }
}

// ---------- kernel 4: main — block-scope gather phase into LDS, then compute ----------
// one block per node, 256 threads = 4 waves; wave w owns h in [w*32, w*32+32)
// Phase 1: cooperatively gather ALL 32KB of neighbor projections into LDS
//          (8192 independent loads in flight per block — one latency exposure).
// Phase 2: MFMA + epilogue reading gathers from LDS (imm-offset ds_read_b32).
__global__ __launch_bounds__(256) void main_kernel(
    const float* __restrict__ nodes,
    const float* __restrict__ rbf_che, const int* __restrict__ idx_che,
    const float* __restrict__ rbf_vdw, const int* __restrict__ idx_vdw,
    const unsigned int* __restrict__ P,
    const unsigned short* __restrict__ Bfrag, const float* __restrict__ biasP,
    float* __restrict__ out) {
    __shared__ unsigned short sA[2 * 32 * 40];    // 5120 B
    __shared__ int sidx[64];                      // 256 B   [b*32+m]
    __shared__ unsigned int sG[64 * 130];         // 33280 B  row b*32+m, stride 130
    int n = blockIdx.x;
    int tid = threadIdx.x;
    int w = tid >> 6, l = tid & 63;       // w in {0..3}
    int lhi = l >> 4, llo = l & 15;
    int wold = w >> 1, whalf = w & 1;

    if (tid < 192) {
        int row = tid / 3, j = tid - row * 3;
        *(uint2*)&sA[row * 40 + 20 + j * 4] = make_uint2(0u, 0u);
    }
    for (int i = tid; i < 320; i += 256) {
        int b = (i >= 160) ? 1 : 0, rem = i - b * 160;
        int m = rem / 5, kq = rem - m * 5;
        const float* src = b ? rbf_vdw : rbf_che;
        float4 v = *(const float4*)&src[n * 640 + m * 20 + kq * 4];
        uint2 p;
        p.x = pack_bf2(v.x, v.y);
        p.y = pack_bf2(v.z, v.w);
        *(uint2*)&sA[(b * 32 + m) * 40 + kq * 4] = p;
    }
    if (tid < 64) {
        int b = tid >> 5, m = tid & 31;
        sidx[tid] = (b ? idx_vdw : idx_che)[n * MM + m];
    }
    __syncthreads();

    // ---- early self/bias loads (in flight under the gather phase) ----
    unsigned int sval[2][2];
    float bF[2][2], bC[2][2];
#pragma unroll
    for (int b = 0; b < 2; ++b) {
        const unsigned int* sp = P + (size_t)n * 512 + b * 256 + w * 32 + llo;
        sval[b][0] = sp[0];
        sval[b][1] = sp[16];
        const float* bfp = biasP + b * 256 + w * 32 + llo;
        bF[b][0] = bfp[0];   bF[b][1] = bfp[16];
        bC[b][0] = bfp[128]; bC[b][1] = bfp[144];
    }

    // ---- phase 1: gather 64 neighbor rows (512 B each) into sG ----
    // thread covers column hp of rows ri0, ri0+2, ..., ri0+62
    {
        int hp = tid & 127;          // column (pair index within row)
        int ri0 = tid >> 7;          // 0 or 1
        const int* sx = sidx + ri0;
        unsigned int* dst = sG + ri0 * 130 + hp;
        unsigned int cofs0 = 512u + 4u * (unsigned)hp;   // byte ofs in P row, b=0 sec
#pragma unroll
        for (int k = 0; k < 32; ++k) {
            int idx = sx[2 * k];                          // LDS broadcast read
            unsigned int cofs = (k < 16) ? cofs0 : cofs0 + 1024u;  // b=1 half
            const unsigned int* src = (const unsigned int*)
                ((const char*)P + ((size_t)idx << 11) + cofs);
            dst[k * 260] = *src;                          // imm ds_write offsets
        }
    }
    __syncthreads();

    // ---- phase 2: MFMA + epilogue (gathers now in LDS) ----
    const unsigned int* sGr = sG + lhi * 4 * 130 + w * 32 + llo;
    float ps0 = 0.f, ps1 = 0.f;

#pragma unroll
    for (int b = 0; b < 2; ++b) {
        bf16x8 Af0 = *(const bf16x8*)&sA[(b * 32 + llo) * 40 + lhi * 8];
        bf16x8 Af1 = *(const bf16x8*)&sA[(b * 32 + 16 + llo) * 40 + lhi * 8];
        const unsigned short* bb = Bfrag + (size_t)((b * 2 + wold) * 8 + whalf * 4) * 512;

#pragma unroll
        for (int ht = 0; ht < 2; ++ht) {
            bf16x8 Bff = *(const bf16x8*)(bb + ((ht * 2) * 64 + l) * 8);
            bf16x8 Bfc = *(const bf16x8*)(bb + ((ht * 2 + 1) * 64 + l) * 8);

            unsigned int su = sval[b][ht];
            float baseF = bF[b][ht] + bf_lo(su);
            float baseC = bC[b][ht] + bf_hi(su);

            f32x4 a0f = {baseF, baseF, baseF, baseF};
            f32x4 a0c = {baseC, baseC, baseC, baseC};
            f32x4 a1f = a0f, a1c = a0c;
            a0f = __builtin_amdgcn_mfma_f32_16x16x32_bf16(Af0, Bff, a0f, 0, 0, 0);
            a0c = __builtin_amdgcn_mfma_f32_16x16x32_bf16(Af0, Bfc, a0c, 0, 0, 0);
            a1f = __builtin_amdgcn_mfma_f32_16x16x32_bf16(Af1, Bff, a1f, 0, 0, 0);
            a1c = __builtin_amdgcn_mfma_f32_16x16x32_bf16(Af1, Bfc, a1c, 0, 0, 0);

            float s = 0.f;
#pragma unroll
            for (int r = 0; r < 4; ++r) {
                unsigned int g = sGr[(b * 32 + r) * 130 + ht * 16];        // tm=0 row
                float filt = a0f[r] + bf_lo(g);
                float core = a0c[r] + bf_hi(g);
                float sg = __builtin_amdgcn_rcpf(1.f + __expf(-filt));
                float sop = softplusf(core);
                s = fmaf(sg, sop, s);
            }
#pragma unroll
            for (int r = 0; r < 4; ++r) {
                unsigned int g = sGr[(b * 32 + 16 + r) * 130 + ht * 16];   // tm=1 row
                float filt = a1f[r] + bf_lo(g);
                float core = a1c[r] + bf_hi(g);
                float sg = __builtin_amdgcn_rcpf(1.f + __expf(-filt));
                float sop = softplusf(core);
                s = fmaf(sg, sop, s);
            }
            if (ht == 0) ps0 += s;
            else ps1 += s;
        }
    }

    float v0 = ps0;
    v0 += __shfl_xor(v0, 16);
    v0 += __shfl_xor(v0, 32);
    float v1 = ps1;
    v1 += __shfl_xor(v1, 16);
    v1 += __shfl_xor(v1, 32);

    if (lhi < 2) {
        int h = w * 32 + lhi * 16 + llo;   // < 128
        float res = lhi ? v1 : v0;
        float x = nodes[n * 128 + h] + res;
        out[n * 128 + h] = softplusf(x);
    }
}

// ---------- launch ----------
extern "C" void kernel_launch(void* const* d_in, const int* in_sizes, int n_in,
                              void* d_out, int out_size, void* d_ws, size_t ws_size,
                              hipStream_t stream) {
    const float* nodes     = (const float*)d_in[0];
    const float* che_rbf   = (const float*)d_in[1];
    const int*   che_idx   = (const int*)d_in[2];
    const float* vdw_rbf   = (const float*)d_in[3];
    const int*   vdw_idx   = (const int*)d_in[4];
    const float* che_Wf    = (const float*)d_in[5];
    const float* che_bf    = (const float*)d_in[6];
    const float* che_Wfull = (const float*)d_in[7];
    const float* che_bfull = (const float*)d_in[8];
    const float* vdw_Wf    = (const float*)d_in[9];
    const float* vdw_bf    = (const float*)d_in[10];
    const float* vdw_Wfull = (const float*)d_in[11];
    const float* vdw_bfull = (const float*)d_in[12];

    char* ws = (char*)d_ws;
    float* Wcat           = (float*)ws;                       // 512 KB
    unsigned short* Bfrag = (unsigned short*)(ws + 524288);   // 32 KB
    float* biasP          = (float*)(ws + 524288 + 32768);    // 2 KB
    unsigned int* P       = (unsigned int*)(ws + 559104);     // 40.96 MB

    build_wcat<<<512, 256, 0, stream>>>(che_Wfull, vdw_Wfull, Wcat);
    build_bfrag<<<8, 256, 0, stream>>>(che_Wf, che_bf, che_Wfull, che_bfull,
                                       vdw_Wf, vdw_bf, vdw_Wfull, vdw_bfull,
                                       Bfrag, biasP);
    proj_kernel<<<NN / 16, 256, 0, stream>>>(nodes, Wcat, P);
    main_kernel<<<NN, 256, 0, stream>>>(nodes, che_rbf, che_idx, vdw_rbf, vdw_idx,
                                        P, Bfrag, biasP, (float*)d_out);
}

// Round 10
// 175.702 us; speedup vs baseline: 1.5627x; 1.5627x over previous
//
#include <hip/hip_runtime.h>
#include <hip/hip_bf16.h>

#define NN 20000
#define MM 32
#define EE 20
#define HH 128
#define LOG2E 1.44269504088896f
#define LN2   0.69314718055995f

typedef __attribute__((ext_vector_type(8))) short bf16x8;
typedef __attribute__((ext_vector_type(4))) float f32x4;

// ---------- helpers ----------
__device__ __forceinline__ float bf_lo(unsigned int u) {
    return __uint_as_float(u << 16);
}
__device__ __forceinline__ float bf_hi(unsigned int u) {
    return __uint_as_float(u & 0xFFFF0000u);
}
__device__ __forceinline__ unsigned int pack_bf2(float lo, float hi) {
    unsigned int a = __float_as_uint(lo);
    unsigned int b = __float_as_uint(hi);
    a += 0x7FFFu + ((a >> 16) & 1u);
    b += 0x7FFFu + ((b >> 16) & 1u);
    return (a >> 16) | (b & 0xFFFF0000u);
}
__device__ __forceinline__ unsigned short bf16r(float v) {
    unsigned int u = __float_as_uint(v);
    u += 0x7FFFu + ((u >> 16) & 1u);
    return (unsigned short)(u >> 16);
}
__device__ __forceinline__ float softplusf(float x) {
    return fmaxf(x, 0.f) + __logf(1.f + __expf(-fabsf(x)));
}

// ---------- kernel 1: build Pfrag — MFMA B fragments of proj weights (bf16) ----------
// Pfrag flat index: ((tile*4+ks)*64 + l)*8 + i   (131072 bf16, 256 KB)
// tile<32: filt (slot0); tile>=32: core (slot1). Pair col j=(tile&31)*16+(l&15);
// b=j>>8, sec=(j>>7)&1, h=j&127; K row = (sec?256:0) + ks*32 + (l>>4)*8 + i.
// Values pre-scaled by LOG2E (exp2/log2 epilogue refactor).
__global__ void build_pfrag(const float* __restrict__ cheW,
                            const float* __restrict__ vdwW,
                            unsigned short* __restrict__ Pfrag) {
    int t = blockIdx.x * 256 + threadIdx.x;   // < 131072
    int i = t & 7;
    int l = (t >> 3) & 63;
    int ks = (t >> 9) & 3;
    int tile = t >> 11;                       // 0..63
    int j = (tile & 31) * 16 + (l & 15);      // pair col < 512
    int slot = tile >> 5;
    int b = j >> 8, sec = (j >> 7) & 1, h = j & 127;
    int klocal = (l >> 4) * 8 + i;
    int row = (sec ? 256 : 0) + ks * 32 + klocal;
    const float* W = b ? vdwW : cheW;
    Pfrag[t] = bf16r(LOG2E * W[row * 256 + slot * 128 + h]);
}

// ---------- kernel 2: build Bfrag (edge-weight MFMA B fragments) + biasP ----------
// Both pre-scaled by LOG2E.
__global__ void build_bfrag(const float* __restrict__ cheWf, const float* __restrict__ cheBf,
                            const float* __restrict__ cheW,  const float* __restrict__ cheBfull,
                            const float* __restrict__ vdwWf, const float* __restrict__ vdwBf,
                            const float* __restrict__ vdwW,  const float* __restrict__ vdwBfull,
                            unsigned short* __restrict__ Bfrag, float* __restrict__ biasP) {
    int t = blockIdx.x * 256 + threadIdx.x;   // < 2048
    int b = t >> 10, w = (t >> 9) & 1, tc = (t >> 6) & 7, l = t & 63;
    int lhi = l >> 4, llo = l & 15;
    int h = w * 64 + (tc >> 1) * 16 + llo;    // < 128
    int slot = tc & 1;
    int jcol = slot * 128 + h;                // < 256
    const float* Wf = b ? vdwWf : cheWf;
    const float* W  = b ? vdwW  : cheW;

    unsigned short o[8];
#pragma unroll
    for (int i = 0; i < 8; ++i) {
        int k = lhi * 8 + i;
        float a = 0.f;
        if (k < EE)
            for (int h2 = 0; h2 < 128; ++h2)
                a = fmaf(Wf[k * 128 + h2], W[(128 + h2) * 256 + jcol], a);
        o[i] = bf16r(LOG2E * a);
    }
#pragma unroll
    for (int i = 0; i < 8; ++i) Bfrag[t * 8 + i] = o[i];

    if (t < 512) {
        int bb = t >> 8, sl = (t >> 7) & 1, hh = t & 127;
        int jc = sl * 128 + hh;
        const float* bfv   = bb ? vdwBf    : cheBf;
        const float* Wb    = bb ? vdwW     : cheW;
        const float* bfull = bb ? vdwBfull : cheBfull;
        float s = bfull[jc];
        for (int h2 = 0; h2 < 128; ++h2)
            s = fmaf(bfv[h2], Wb[(128 + h2) * 256 + jc], s);
        biasP[t] = LOG2E * s;
    }
}

// ---------- kernel 3: proj GEMM via MFMA — P[n][512] = bf16pack(nodes @ W) ----------
// 16 nodes/block, 256 thr = 4 waves; wave w covers pair cols [w*128, w*128+128).
__global__ __launch_bounds__(256) void proj_mfma(const float* __restrict__ nodes,
                                                 const unsigned short* __restrict__ Pfrag,
                                                 unsigned int* __restrict__ P) {
    __shared__ unsigned short ln[16 * 136];   // nodes tile bf16, padded stride
    int n0 = blockIdx.x * 16;
    int t = threadIdx.x;
    {
        int row = t >> 4, seg = t & 15;
        const float* src = &nodes[(n0 + row) * 128 + seg * 8];
        float4 v0 = *(const float4*)src;
        float4 v1 = *(const float4*)(src + 4);
        uint4 u;
        u.x = pack_bf2(v0.x, v0.y);
        u.y = pack_bf2(v0.z, v0.w);
        u.z = pack_bf2(v1.x, v1.y);
        u.w = pack_bf2(v1.z, v1.w);
        *(uint4*)&ln[row * 136 + seg * 8] = u;
    }
    __syncthreads();

    int w = t >> 6, l = t & 63, lhi = l >> 4, llo = l & 15;
    bf16x8 Af[4];
#pragma unroll
    for (int ks = 0; ks < 4; ++ks)
        Af[ks] = *(const bf16x8*)&ln[llo * 136 + ks * 32 + lhi * 8];

#pragma unroll
    for (int tp = 0; tp < 8; ++tp) {
        int ft = w * 8 + tp;        // filt tile
        int ct = 32 + w * 8 + tp;   // core tile
        f32x4 cf = {0.f, 0.f, 0.f, 0.f};
        f32x4 cc = {0.f, 0.f, 0.f, 0.f};
#pragma unroll
        for (int ks = 0; ks < 4; ++ks) {
            bf16x8 Bf = *(const bf16x8*)&Pfrag[((ft * 4 + ks) * 64 + l) * 8];
            bf16x8 Bc = *(const bf16x8*)&Pfrag[((ct * 4 + ks) * 64 + l) * 8];
            cf = __builtin_amdgcn_mfma_f32_16x16x32_bf16(Af[ks], Bf, cf, 0, 0, 0);
            cc = __builtin_amdgcn_mfma_f32_16x16x32_bf16(Af[ks], Bc, cc, 0, 0, 0);
        }
        int j = w * 128 + tp * 16 + llo;   // pair col
#pragma unroll
        for (int r = 0; r < 4; ++r)
            P[(size_t)(n0 + lhi * 4 + r) * 512 + j] = pack_bf2(cf[r], cc[r]);
    }
}

// ---------- kernel 4: main — R7 structure + exp2/log2 epilogue ----------
// one block per node, 256 threads = 4 waves; wave w owns h in [w*32, w*32+32)
__global__ __launch_bounds__(256) void main_kernel(
    const float* __restrict__ nodes,
    const float* __restrict__ rbf_che, const int* __restrict__ idx_che,
    const float* __restrict__ rbf_vdw, const int* __restrict__ idx_vdw,
    const unsigned int* __restrict__ P,
    const unsigned short* __restrict__ Bfrag, const float* __restrict__ biasP,
    float* __restrict__ out) {
    __shared__ unsigned short sA[2 * 32 * 40];
    __shared__ int sidx[2][MM];
    int n = blockIdx.x;
    int tid = threadIdx.x;
    int w = tid >> 6, l = tid & 63;       // w in {0..3}
    int lhi = l >> 4, llo = l & 15;
    int wold = w >> 1, whalf = w & 1;

    if (tid < 192) {
        int row = tid / 3, j = tid - row * 3;
        *(uint2*)&sA[row * 40 + 20 + j * 4] = make_uint2(0u, 0u);
    }
    for (int i = tid; i < 320; i += 256) {
        int b = (i >= 160) ? 1 : 0, rem = i - b * 160;
        int m = rem / 5, kq = rem - m * 5;
        const float* src = b ? rbf_vdw : rbf_che;
        float4 v = *(const float4*)&src[n * 640 + m * 20 + kq * 4];
        uint2 p;
        p.x = pack_bf2(v.x, v.y);
        p.y = pack_bf2(v.z, v.w);
        *(uint2*)&sA[(b * 32 + m) * 40 + kq * 4] = p;
    }
    if (tid < 64) {
        int b = tid >> 5, m = tid & 31;
        sidx[b][m] = (b ? idx_vdw : idx_che)[n * MM + m];
    }
    __syncthreads();

    float ps0 = 0.f, ps1 = 0.f;

#pragma unroll
    for (int b = 0; b < 2; ++b) {
        bf16x8 Af0 = *(const bf16x8*)&sA[(b * 32 + llo) * 40 + lhi * 8];
        bf16x8 Af1 = *(const bf16x8*)&sA[(b * 32 + 16 + llo) * 40 + lhi * 8];
        int4 vi0 = *(const int4*)&sidx[b][lhi * 4];
        int4 vi1 = *(const int4*)&sidx[b][16 + lhi * 4];

        int secofs = b * 256 + 128 + w * 32 + llo;
        const unsigned int* gp[8];
        gp[0] = P + (size_t)vi0.x * 512 + secofs;
        gp[1] = P + (size_t)vi0.y * 512 + secofs;
        gp[2] = P + (size_t)vi0.z * 512 + secofs;
        gp[3] = P + (size_t)vi0.w * 512 + secofs;
        gp[4] = P + (size_t)vi1.x * 512 + secofs;
        gp[5] = P + (size_t)vi1.y * 512 + secofs;
        gp[6] = P + (size_t)vi1.z * 512 + secofs;
        gp[7] = P + (size_t)vi1.w * 512 + secofs;

        const unsigned int* sp = P + (size_t)n * 512 + b * 256 + w * 32 + llo;
        const float* bfp = biasP + b * 256 + w * 32 + llo;
        const unsigned short* bb = Bfrag + (size_t)((b * 2 + wold) * 8 + whalf * 4) * 512;

#pragma unroll
        for (int ht = 0; ht < 2; ++ht) {
            bf16x8 Bff = *(const bf16x8*)(bb + ((ht * 2) * 64 + l) * 8);
            bf16x8 Bfc = *(const bf16x8*)(bb + ((ht * 2 + 1) * 64 + l) * 8);

            unsigned int su = sp[ht * 16];
            float baseF = bfp[ht * 16]       + bf_lo(su);
            float baseC = bfp[ht * 16 + 128] + bf_hi(su);

            f32x4 a0f = {baseF, baseF, baseF, baseF};
            f32x4 a0c = {baseC, baseC, baseC, baseC};
            f32x4 a1f = a0f, a1c = a0c;
            a0f = __builtin_amdgcn_mfma_f32_16x16x32_bf16(Af0, Bff, a0f, 0, 0, 0);
            a0c = __builtin_amdgcn_mfma_f32_16x16x32_bf16(Af0, Bfc, a0c, 0, 0, 0);
            a1f = __builtin_amdgcn_mfma_f32_16x16x32_bf16(Af1, Bff, a1f, 0, 0, 0);
            a1c = __builtin_amdgcn_mfma_f32_16x16x32_bf16(Af1, Bfc, a1c, 0, 0, 0);

            float s = 0.f;
            // filt', core' are log2e-scaled: exp2/log2 direct, ln2 factored out
#pragma unroll
            for (int r = 0; r < 4; ++r) {
                unsigned int g = gp[r][ht * 16];
                float filt = a0f[r] + bf_lo(g);
                float core = a0c[r] + bf_hi(g);
                float sg = __builtin_amdgcn_rcpf(1.f + __builtin_amdgcn_exp2f(-filt));
                float sop = fmaxf(core, 0.f) +
                            __builtin_amdgcn_logf(1.f + __builtin_amdgcn_exp2f(-fabsf(core)));
                s = fmaf(sg, sop, s);
            }
#pragma unroll
            for (int r = 0; r < 4; ++r) {
                unsigned int g = gp[4 + r][ht * 16];
                float filt = a1f[r] + bf_lo(g);
                float core = a1c[r] + bf_hi(g);
                float sg = __builtin_amdgcn_rcpf(1.f + __builtin_amdgcn_exp2f(-filt));
                float sop = fmaxf(core, 0.f) +
                            __builtin_amdgcn_logf(1.f + __builtin_amdgcn_exp2f(-fabsf(core)));
                s = fmaf(sg, sop, s);
            }
            if (ht == 0) ps0 += s;
            else ps1 += s;
        }
    }

    float v0 = ps0;
    v0 += __shfl_xor(v0, 16);
    v0 += __shfl_xor(v0, 32);
    float v1 = ps1;
    v1 += __shfl_xor(v1, 16);
    v1 += __shfl_xor(v1, 32);

    if (lhi < 2) {
        int h = w * 32 + lhi * 16 + llo;   // < 128
        float res = lhi ? v1 : v0;
        float x = nodes[n * 128 + h] + LN2 * res;   // undo log2e scale once
        out[n * 128 + h] = softplusf(x);
    }
}

// ---------- launch ----------
extern "C" void kernel_launch(void* const* d_in, const int* in_sizes, int n_in,
                              void* d_out, int out_size, void* d_ws, size_t ws_size,
                              hipStream_t stream) {
    const float* nodes     = (const float*)d_in[0];
    const float* che_rbf   = (const float*)d_in[1];
    const int*   che_idx   = (const int*)d_in[2];
    const float* vdw_rbf   = (const float*)d_in[3];
    const int*   vdw_idx   = (const int*)d_in[4];
    const float* che_Wf    = (const float*)d_in[5];
    const float* che_bf    = (const float*)d_in[6];
    const float* che_Wfull = (const float*)d_in[7];
    const float* che_bfull = (const float*)d_in[8];
    const float* vdw_Wf    = (const float*)d_in[9];
    const float* vdw_bf    = (const float*)d_in[10];
    const float* vdw_Wfull = (const float*)d_in[11];
    const float* vdw_bfull = (const float*)d_in[12];

    char* ws = (char*)d_ws;
    unsigned short* Pfrag = (unsigned short*)ws;              // 256 KB
    unsigned short* Bfrag = (unsigned short*)(ws + 262144);   // 32 KB
    float* biasP          = (float*)(ws + 294912);            // 2 KB
    unsigned int* P       = (unsigned int*)(ws + 299008);     // 40.96 MB

    build_pfrag<<<512, 256, 0, stream>>>(che_Wfull, vdw_Wfull, Pfrag);
    build_bfrag<<<8, 256, 0, stream>>>(che_Wf, che_bf, che_Wfull, che_bfull,
                                       vdw_Wf, vdw_bf, vdw_Wfull, vdw_bfull,
                                       Bfrag, biasP);
    proj_mfma<<<NN / 16, 256, 0, stream>>>(nodes, Pfrag, P);
    main_kernel<<<NN, 256, 0, stream>>>(nodes, che_rbf, che_idx, vdw_rbf, vdw_idx,
                                        P, Bfrag, biasP, (float*)d_out);
}